// Round 5
// baseline (106.268 us; speedup 1.0000x reference)
//
#include <hip/hip_runtime.h>

#define T_TOK 65536
#define DDIM 512
#define NEXP 8
#define CAP 16384

__device__ inline float wave_sum(float v) {
#pragma unroll
  for (int m = 1; m < 64; m <<= 1) v += __shfl_xor(v, m, 64);
  return v;
}

__device__ __forceinline__ void async_cp16(const float* g, void* l) {
  __builtin_amdgcn_global_load_lds(
      (const __attribute__((address_space(1))) void*)g,
      (__attribute__((address_space(3))) void*)l, 16, 0, 0);
}

// --- K0t: transpose gate weights: wT[e*512+d] = Wg[d*8+e] (rows 0..7) ---
__global__ void k_wgT(const float* __restrict__ Wg, float* __restrict__ wT) {
  int i = blockIdx.x * 256 + threadIdx.x;  // < 4096
  int e = i >> 9, d = i & 511;
  wT[i] = Wg[d * 8 + e];
}

// --- K0a: w2s[e*H+h] = sum_d W2[e,h,d]; one wave per row, 4096 rows ---
__global__ void k_w2s(const float* __restrict__ W2, float* __restrict__ w2s) {
  int w = threadIdx.x >> 6, lane = threadIdx.x & 63;
  int row = blockIdx.x * 4 + w;  // < 4096
  const float* p = W2 + (size_t)row * 512;
  float sum = 0.f;
#pragma unroll
  for (int j = 0; j < 8; ++j) sum += p[lane + j * 64];
  sum = wave_sum(sum);
  if (lane == 0) w2s[row] = sum;
}

// --- K0b: wT[(8+e)*512+d] = sum_h W1[e,d,h]*w2s[e,h]; last block: beta[e] ---
__global__ void k_v_beta(const float* __restrict__ W1, const float* __restrict__ b1,
                         const float* __restrict__ b2, const float* __restrict__ w2s,
                         float* __restrict__ wT, float* __restrict__ beta) {
  int w = threadIdx.x >> 6, lane = threadIdx.x & 63;
  if (blockIdx.x < 1024) {
    int rid = blockIdx.x * 4 + w;  // rid = e*512 + d
    int e = rid >> 9, d = rid & 511;
    const float* p = W1 + (size_t)rid * 512;
    const float* q = w2s + e * 512;
    float sum = 0.f;
#pragma unroll
    for (int j = 0; j < 8; ++j) { int h = lane + j * 64; sum += p[h] * q[h]; }
    sum = wave_sum(sum);
    if (lane == 0) wT[(size_t)(8 + e) * 512 + d] = sum;
  } else {
    // beta[e] = sum_h b1[e,h]*w2s[e,h] + sum_d b2[e,d]
#pragma unroll
    for (int r = 0; r < 2; ++r) {
      int e = w + r * 4;
      float sum = 0.f;
#pragma unroll
      for (int j = 0; j < 8; ++j) {
        int i = lane + j * 64;
        sum += b1[e * 512 + i] * w2s[e * 512 + i] + b2[e * 512 + i];
      }
      sum = wave_sum(sum);
      if (lane == 0) beta[e] = sum;
    }
  }
}

// --- K1: per token 16 dots ([0..7]=logits, [8..15]=x·v), lane = token.
// One independent wave per block (64 tokens); weights via wave-uniform s_load
// from wT[16][512]; x staged by global_load_lds DMA, double-buffered,
// 16 chunks of 32 floats, XOR-8 swizzle (both-sides: pre-swizzled global
// source + swizzled LDS read) -> conflict-free ds_read_b128, no barriers.
__global__ __launch_bounds__(64) void k_dots(const float* __restrict__ x,
                                             const float* __restrict__ wT,
                                             float* __restrict__ dots) {
  __shared__ float4 sX[2][512];  // 2 x 8 KB
  const int lane = threadIdx.x & 63;
  const int t0 = blockIdx.x * 64;
  // DMA instr k, lane i: token = t0 + 8k + (i>>3); phys f4 slot = i&7;
  // logical f4 = (i&7) ^ ((i>>3)&7)  (== phys ^ (token&7)).
  const float* g0 = x + (size_t)(t0 + (lane >> 3)) * 512 +
                    4 * ((lane & 7) ^ ((lane >> 3) & 7));
  float acc[16];
#pragma unroll
  for (int o = 0; o < 16; ++o) acc[o] = 0.f;

  // prologue: chunk 0 -> buf 0
#pragma unroll
  for (int k = 0; k < 8; ++k) async_cp16(g0 + k * 4096, &sX[0][k * 64]);
  asm volatile("s_waitcnt vmcnt(0)" ::: "memory");

  for (int c = 0; c < 16; ++c) {
    int b = c & 1;
    if (c < 15) {  // prefetch next chunk into other buffer
#pragma unroll
      for (int k = 0; k < 8; ++k)
        async_cp16(g0 + (c + 1) * 32 + k * 4096, &sX[b ^ 1][k * 64]);
    }
    const float4* row = &sX[b][lane * 8];
#pragma unroll
    for (int j = 0; j < 8; ++j) {
      float4 xv = row[j ^ (lane & 7)];
      const float* wp = wT + c * 32 + j * 4;
#pragma unroll
      for (int o = 0; o < 16; ++o) {
        float4 w = *reinterpret_cast<const float4*>(wp + o * 512);
        acc[o] += xv.x * w.x + xv.y * w.y + xv.z * w.z + xv.w * w.w;
      }
    }
    asm volatile("s_waitcnt vmcnt(0)" ::: "memory");  // next chunk landed
  }

  float4* op = reinterpret_cast<float4*>(dots + (size_t)(t0 + lane) * 16);
#pragma unroll
  for (int q = 0; q < 4; ++q) {
    float4 o4;
    o4.x = acc[q * 4 + 0]; o4.y = acc[q * 4 + 1];
    o4.z = acc[q * 4 + 2]; o4.w = acc[q * 4 + 3];
    op[q] = o4;
  }
}

// --- K2a: top-2 select + renorm weights + per-block expert histograms ---
__global__ void k_top2(const float* __restrict__ dots, const float* __restrict__ beta,
                       float4* __restrict__ wd, int* __restrict__ epk,
                       int* __restrict__ hist) {
  __shared__ int c0[8], c1[8];
  int tid = threadIdx.x;
  if (tid < 8) { c0[tid] = 0; c1[tid] = 0; }
  __syncthreads();
  int t = blockIdx.x * 256 + tid;
  const float* p = dots + (size_t)t * 16;
  float l[8], dv[8];
#pragma unroll
  for (int e = 0; e < 8; ++e) { l[e] = p[e]; dv[e] = p[8 + e]; }
  int e1 = 0; float v1 = l[0];
#pragma unroll
  for (int e = 1; e < 8; ++e) if (l[e] > v1) { v1 = l[e]; e1 = e; }  // ties -> low idx
  int e2 = 0; float v2 = -3.4e38f;
#pragma unroll
  for (int e = 0; e < 8; ++e) if (e != e1 && l[e] > v2) { v2 = l[e]; e2 = e; }
  float wexp = expf(v2 - v1);           // g2/g1 after softmax; renorm over top-2
  float w1 = 1.f / (1.f + wexp);
  float w2 = wexp * w1;
  float d1 = 0.f, d2 = 0.f;
#pragma unroll
  for (int e = 0; e < 8; ++e) {
    d1 = (e == e1) ? dv[e] : d1;
    d2 = (e == e2) ? dv[e] : d2;
  }
  float4 o; o.x = w1; o.y = w2; o.z = d1 + beta[e1]; o.w = d2 + beta[e2];
  wd[t] = o;
  epk[t] = e1 | (e2 << 8);
  atomicAdd(&c0[e1], 1);
  atomicAdd(&c1[e2], 1);
  __syncthreads();
  if (tid < 8) {
    hist[blockIdx.x * 8 + tid] = c0[tid];
    hist[(256 + blockIdx.x) * 8 + tid] = c1[tid];
  }
}

// --- K2b: exclusive scan of 512 block-histograms (k-major order), per expert ---
__global__ void k_scan(const int* __restrict__ hist, int* __restrict__ off) {
  __shared__ int sH[4096];
  __shared__ int sT[256];
  int tid = threadIdx.x;
  for (int i = tid; i < 4096; i += 256) sH[i] = hist[i];
  __syncthreads();
  int e = tid & 7, g = tid >> 3;  // g < 32, each scans 16 rows
  int run = 0;
  for (int i = g * 16; i < g * 16 + 16; ++i) {
    int cv = sH[i * 8 + e]; sH[i * 8 + e] = run; run += cv;
  }
  sT[g * 8 + e] = run;
  __syncthreads();
  if (tid < 8) {
    int run2 = 0;
    for (int g2 = 0; g2 < 32; ++g2) {
      int cv = sT[g2 * 8 + tid]; sT[g2 * 8 + tid] = run2; run2 += cv;
    }
  }
  __syncthreads();
  int add = sT[g * 8 + e];
  for (int i = g * 16; i < g * 16 + 16; ++i) sH[i * 8 + e] += add;
  __syncthreads();
  for (int i = tid; i < 4096; i += 256) off[i] = sH[i];
}

// --- K2c: stable intra-block ranks via ballots -> pos -> keep -> s[t] ---
__global__ void k_keep(const int* __restrict__ epk, const float4* __restrict__ wd,
                       const int* __restrict__ off, float* __restrict__ s) {
  __shared__ int sC0[32], sC1[32];
  int tid = threadIdx.x, lane = tid & 63, w = tid >> 6;
  int t = blockIdx.x * 256 + tid;
  int ep = epk[t]; int e1 = ep & 255, e2 = ep >> 8;
  unsigned long long lt = (1ull << lane) - 1ull;
  int wr0 = 0, wr1 = 0;
#pragma unroll
  for (int e = 0; e < 8; ++e) {
    unsigned long long m0 = __ballot(e1 == e);
    unsigned long long m1 = __ballot(e2 == e);
    if (e == e1) wr0 = __popcll(m0 & lt);
    if (e == e2) wr1 = __popcll(m1 & lt);
    if (lane == 0) { sC0[w * 8 + e] = __popcll(m0); sC1[w * 8 + e] = __popcll(m1); }
  }
  __syncthreads();
  int woff0 = 0, woff1 = 0;
  for (int wp = 0; wp < 4; ++wp) {
    if (wp < w) { woff0 += sC0[wp * 8 + e1]; woff1 += sC1[wp * 8 + e2]; }
  }
  int b = blockIdx.x;
  int pos0 = off[b * 8 + e1] + woff0 + wr0;
  int pos1 = off[(256 + b) * 8 + e2] + woff1 + wr1;
  float4 v = wd[t];
  float sv = 0.f;
  if (pos0 < CAP) sv += v.x * v.z;
  if (pos1 < CAP) sv += v.y * v.w;
  s[t] = sv;
}

// --- K3: per-row (B=8 rows of N=8192) log_softmax ---
__global__ __launch_bounds__(1024) void k_lsm(const float* __restrict__ s,
                                              float* __restrict__ out) {
  __shared__ float sRa[16], sRb[16];
  int tid = threadIdx.x, lane = tid & 63, w = tid >> 6;
  size_t base = (size_t)blockIdx.x * 8192;
  float v[8];
#pragma unroll
  for (int j = 0; j < 8; ++j) v[j] = s[base + tid + j * 1024];
  float mx = v[0];
#pragma unroll
  for (int j = 1; j < 8; ++j) mx = fmaxf(mx, v[j]);
#pragma unroll
  for (int m = 1; m < 64; m <<= 1) mx = fmaxf(mx, __shfl_xor(mx, m, 64));
  if (lane == 0) sRa[w] = mx;
  __syncthreads();
#pragma unroll
  for (int i = 0; i < 16; ++i) mx = fmaxf(mx, sRa[i]);
  float sum = 0.f;
#pragma unroll
  for (int j = 0; j < 8; ++j) sum += expf(v[j] - mx);
#pragma unroll
  for (int m = 1; m < 64; m <<= 1) sum += __shfl_xor(sum, m, 64);
  if (lane == 0) sRb[w] = sum;
  __syncthreads();
  float tot = 0.f;
#pragma unroll
  for (int i = 0; i < 16; ++i) tot += sRb[i];
  float lse = logf(tot);
#pragma unroll
  for (int j = 0; j < 8; ++j) out[base + tid + j * 1024] = v[j] - mx - lse;
}

extern "C" void kernel_launch(void* const* d_in, const int* in_sizes, int n_in,
                              void* d_out, int out_size, void* d_ws, size_t ws_size,
                              hipStream_t stream) {
  const float* x  = (const float*)d_in[0];
  const float* Wg = (const float*)d_in[1];
  const float* W1 = (const float*)d_in[2];
  const float* b1 = (const float*)d_in[3];
  const float* W2 = (const float*)d_in[4];
  const float* b2 = (const float*)d_in[5];
  float* out = (float*)d_out;
  char* ws = (char*)d_ws;

  float*  w2s  = (float*)(ws);                          // 16 KB
  float*  wT   = (float*)(ws + (16u << 10));            // 32 KB: [16][512]
  float*  beta = (float*)(ws + (48u << 10));            // 32 B
  float*  dots = (float*)(ws + (64u << 10));            // 4 MB
  char*   p1   = ws + (64u << 10) + (4u << 20);
  float4* wd   = (float4*)(p1);                         // 1 MB
  int*    epk  = (int*)(p1 + (1u << 20));               // 256 KB
  int*    hist = (int*)(p1 + (1u << 20) + (256u << 10));// 16 KB
  int*    offa = (int*)(p1 + (1u << 20) + (272u << 10));// 16 KB
  float*  s    = (float*)(p1 + (1u << 20) + (288u << 10)); // 256 KB

  hipLaunchKernelGGL(k_wgT,    dim3(16),   dim3(256),  0, stream, Wg, wT);
  hipLaunchKernelGGL(k_w2s,    dim3(1024), dim3(256),  0, stream, W2, w2s);
  hipLaunchKernelGGL(k_v_beta, dim3(1025), dim3(256),  0, stream, W1, b1, b2, w2s, wT, beta);
  hipLaunchKernelGGL(k_dots,   dim3(1024), dim3(64),   0, stream, x, wT, dots);
  hipLaunchKernelGGL(k_top2,   dim3(256),  dim3(256),  0, stream, dots, beta, wd, epk, hist);
  hipLaunchKernelGGL(k_scan,   dim3(1),    dim3(256),  0, stream, hist, offa);
  hipLaunchKernelGGL(k_keep,   dim3(256),  dim3(256),  0, stream, epk, wd, offa, s);
  hipLaunchKernelGGL(k_lsm,    dim3(8),    dim3(1024), 0, stream, s, out);
}

// Round 6
// 60.150 us; speedup vs baseline: 1.7667x; 1.7667x over previous
//
#include <hip/hip_runtime.h>

#define T_TOK 65536
#define DDIM 512
#define NEXP 8
#define CAP 16384

__device__ inline float wave_sum(float v) {
#pragma unroll
  for (int m = 1; m < 64; m <<= 1) v += __shfl_xor(v, m, 64);
  return v;
}

template <int CTRL>
__device__ __forceinline__ float dppf(float v) {
  return __int_as_float(
      __builtin_amdgcn_mov_dpp(__float_as_int(v), CTRL, 0xf, 0xf, true));
}
__device__ __forceinline__ void pl32swap(float& a, float& b) {
  asm("v_permlane32_swap_b32 %0, %1" : "+v"(a), "+v"(b));
}
__device__ __forceinline__ void pl16swap(float& a, float& b) {
  asm("v_permlane16_swap_b32 %0, %1" : "+v"(a), "+v"(b));
}

// --- K0t: transpose gate weights: wT[e*512+d] = Wg[d*8+e] (rows 0..7) ---
__global__ void k_wgT(const float* __restrict__ Wg, float* __restrict__ wT) {
  int i = blockIdx.x * 256 + threadIdx.x;  // < 4096
  int e = i >> 9, d = i & 511;
  wT[i] = Wg[d * 8 + e];
}

// --- K0a: w2s[e*H+h] = sum_d W2[e,h,d]; one wave per row, 4096 rows ---
__global__ void k_w2s(const float* __restrict__ W2, float* __restrict__ w2s) {
  int w = threadIdx.x >> 6, lane = threadIdx.x & 63;
  int row = blockIdx.x * 4 + w;  // < 4096
  const float* p = W2 + (size_t)row * 512;
  float sum = 0.f;
#pragma unroll
  for (int j = 0; j < 8; ++j) sum += p[lane + j * 64];
  sum = wave_sum(sum);
  if (lane == 0) w2s[row] = sum;
}

// --- K0b: wT[(8+e)*512+d] = sum_h W1[e,d,h]*w2s[e,h]; last block: beta[e] ---
__global__ void k_v_beta(const float* __restrict__ W1, const float* __restrict__ b1,
                         const float* __restrict__ b2, const float* __restrict__ w2s,
                         float* __restrict__ wT, float* __restrict__ beta) {
  int w = threadIdx.x >> 6, lane = threadIdx.x & 63;
  if (blockIdx.x < 1024) {
    int rid = blockIdx.x * 4 + w;  // rid = e*512 + d
    int e = rid >> 9, d = rid & 511;
    const float* p = W1 + (size_t)rid * 512;
    const float* q = w2s + e * 512;
    float sum = 0.f;
#pragma unroll
    for (int j = 0; j < 8; ++j) { int h = lane + j * 64; sum += p[h] * q[h]; }
    sum = wave_sum(sum);
    if (lane == 0) wT[(size_t)(8 + e) * 512 + d] = sum;
  } else {
#pragma unroll
    for (int r = 0; r < 2; ++r) {
      int e = w + r * 4;
      float sum = 0.f;
#pragma unroll
      for (int j = 0; j < 8; ++j) {
        int i = lane + j * 64;
        sum += b1[e * 512 + i] * w2s[e * 512 + i] + b2[e * 512 + i];
      }
      sum = wave_sum(sum);
      if (lane == 0) beta[e] = sum;
    }
  }
}

// --- K1: per token 16 dots ([0..7]=logits, [8..15]=x·v).
// Weights-in-registers streaming GEMV: lane l owns dims [8l,8l+8) (128 w-regs);
// each wave streams 32 contiguous tokens (2 coalesced b128 loads/token,
// register ping-pong prefetch, no LDS, no barriers). Per-token 16 dot sums
// via pure-VALU multi-value butterfly: permlane32/16_swap + DPP
// (row_ror:8 / row_half_mirror / quad_perm), masks {32,16,8,7,2,1}.
__global__ __launch_bounds__(256, 2) void k_dots(const float* __restrict__ x,
                                                 const float* __restrict__ wT,
                                                 float* __restrict__ dots) {
  const int lane = threadIdx.x & 63;
  const int wid = blockIdx.x * 4 + (threadIdx.x >> 6);
  const int tbase = wid * 32;

  float w[16][8];
#pragma unroll
  for (int o = 0; o < 16; ++o) {
    float4 wa = *reinterpret_cast<const float4*>(wT + o * 512 + 8 * lane);
    float4 wb = *reinterpret_cast<const float4*>(wT + o * 512 + 8 * lane + 4);
    w[o][0] = wa.x; w[o][1] = wa.y; w[o][2] = wa.z; w[o][3] = wa.w;
    w[o][4] = wb.x; w[o][5] = wb.y; w[o][6] = wb.z; w[o][7] = wb.w;
  }

  const bool b3 = (lane & 8) != 0;   // keep-bit for ror8 stage
  const bool b2l = (lane & 4) != 0;  // keep-bit for half_mirror stage
  const float* xb = x + (size_t)tbase * 512 + 8 * lane;

  auto proc = [&](int tok, float4 x0, float4 x1) {
    float p[16];
#pragma unroll
    for (int o = 0; o < 16; ++o)
      p[o] = x0.x * w[o][0] + x0.y * w[o][1] + x0.z * w[o][2] + x0.w * w[o][3] +
             x1.x * w[o][4] + x1.y * w[o][5] + x1.z * w[o][6] + x1.w * w[o][7];
    // A: mask 32 (o bit3 <- lane bit5)
    float a[8];
#pragma unroll
    for (int j = 0; j < 8; ++j) {
      float u = p[j], v = p[j + 8];
      pl32swap(u, v);
      a[j] = u + v;
    }
    // B: mask 16 (o bit2 <- lane bit4)
    float b[4];
#pragma unroll
    for (int j = 0; j < 4; ++j) {
      float u = a[j], v = a[j + 4];
      pl16swap(u, v);
      b[j] = u + v;
    }
    // C: mask 8 via row_ror:8 (o bit1 <- lane bit3)
    float c[2];
#pragma unroll
    for (int j = 0; j < 2; ++j) {
      float snd = b3 ? b[j] : b[j + 2];
      float kp  = b3 ? b[j + 2] : b[j];
      c[j] = kp + dppf<0x128>(snd);  // row_ror:8 == l^8 within row
    }
    // D: mask 7 via row_half_mirror (o bit0 <- lane bit2)
    {
      float snd = b2l ? c[0] : c[1];
      float kp  = b2l ? c[1] : c[0];
      float d = kp + dppf<0x141>(snd);  // l^7
      float e = d + dppf<0x4E>(d);      // quad_perm [2,3,0,1] == l^2
      float f = e + dppf<0xB1>(e);      // quad_perm [1,0,3,2] == l^1
      if ((lane & 3) == 0) dots[(size_t)tok * 16 + (lane >> 2)] = f;
    }
  };

  float4 xa0 = *reinterpret_cast<const float4*>(xb);
  float4 xa1 = *reinterpret_cast<const float4*>(xb + 4);
  for (int r = 0; r < 32; r += 2) {
    const float* q1 = xb + (size_t)(r + 1) * 512;
    float4 xb0 = *reinterpret_cast<const float4*>(q1);
    float4 xb1 = *reinterpret_cast<const float4*>(q1 + 4);
    proc(tbase + r, xa0, xa1);
    if (r + 2 < 32) {
      const float* q2 = xb + (size_t)(r + 2) * 512;
      xa0 = *reinterpret_cast<const float4*>(q2);
      xa1 = *reinterpret_cast<const float4*>(q2 + 4);
    }
    proc(tbase + r + 1, xb0, xb1);
  }
}

// --- K2a: top-2 select + renorm weights + per-block expert histograms ---
__global__ void k_top2(const float* __restrict__ dots, const float* __restrict__ beta,
                       float4* __restrict__ wd, int* __restrict__ epk,
                       int* __restrict__ hist) {
  __shared__ int c0[8], c1[8];
  int tid = threadIdx.x;
  if (tid < 8) { c0[tid] = 0; c1[tid] = 0; }
  __syncthreads();
  int t = blockIdx.x * 256 + tid;
  const float* p = dots + (size_t)t * 16;
  float l[8], dv[8];
#pragma unroll
  for (int e = 0; e < 8; ++e) { l[e] = p[e]; dv[e] = p[8 + e]; }
  int e1 = 0; float v1 = l[0];
#pragma unroll
  for (int e = 1; e < 8; ++e) if (l[e] > v1) { v1 = l[e]; e1 = e; }  // ties -> low idx
  int e2 = 0; float v2 = -3.4e38f;
#pragma unroll
  for (int e = 0; e < 8; ++e) if (e != e1 && l[e] > v2) { v2 = l[e]; e2 = e; }
  float wexp = expf(v2 - v1);
  float w1 = 1.f / (1.f + wexp);
  float w2 = wexp * w1;
  float d1 = 0.f, d2 = 0.f;
#pragma unroll
  for (int e = 0; e < 8; ++e) {
    d1 = (e == e1) ? dv[e] : d1;
    d2 = (e == e2) ? dv[e] : d2;
  }
  float4 o; o.x = w1; o.y = w2; o.z = d1 + beta[e1]; o.w = d2 + beta[e2];
  wd[t] = o;
  epk[t] = e1 | (e2 << 8);
  atomicAdd(&c0[e1], 1);
  atomicAdd(&c1[e2], 1);
  __syncthreads();
  if (tid < 8) {
    hist[blockIdx.x * 8 + tid] = c0[tid];
    hist[(256 + blockIdx.x) * 8 + tid] = c1[tid];
  }
}

// --- K2b: exclusive scan of 512 block-histograms (k-major order), per expert ---
__global__ void k_scan(const int* __restrict__ hist, int* __restrict__ off) {
  __shared__ int sH[4096];
  __shared__ int sT[256];
  int tid = threadIdx.x;
  for (int i = tid; i < 4096; i += 256) sH[i] = hist[i];
  __syncthreads();
  int e = tid & 7, g = tid >> 3;
  int run = 0;
  for (int i = g * 16; i < g * 16 + 16; ++i) {
    int cv = sH[i * 8 + e]; sH[i * 8 + e] = run; run += cv;
  }
  sT[g * 8 + e] = run;
  __syncthreads();
  if (tid < 8) {
    int run2 = 0;
    for (int g2 = 0; g2 < 32; ++g2) {
      int cv = sT[g2 * 8 + tid]; sT[g2 * 8 + tid] = run2; run2 += cv;
    }
  }
  __syncthreads();
  int add = sT[g * 8 + e];
  for (int i = g * 16; i < g * 16 + 16; ++i) sH[i * 8 + e] += add;
  __syncthreads();
  for (int i = tid; i < 4096; i += 256) off[i] = sH[i];
}

// --- K2c: stable intra-block ranks via ballots -> pos -> keep -> s[t] ---
__global__ void k_keep(const int* __restrict__ epk, const float4* __restrict__ wd,
                       const int* __restrict__ off, float* __restrict__ s) {
  __shared__ int sC0[32], sC1[32];
  int tid = threadIdx.x, lane = tid & 63, w = tid >> 6;
  int t = blockIdx.x * 256 + tid;
  int ep = epk[t]; int e1 = ep & 255, e2 = ep >> 8;
  unsigned long long lt = (1ull << lane) - 1ull;
  int wr0 = 0, wr1 = 0;
#pragma unroll
  for (int e = 0; e < 8; ++e) {
    unsigned long long m0 = __ballot(e1 == e);
    unsigned long long m1 = __ballot(e2 == e);
    if (e == e1) wr0 = __popcll(m0 & lt);
    if (e == e2) wr1 = __popcll(m1 & lt);
    if (lane == 0) { sC0[w * 8 + e] = __popcll(m0); sC1[w * 8 + e] = __popcll(m1); }
  }
  __syncthreads();
  int woff0 = 0, woff1 = 0;
  for (int wp = 0; wp < 4; ++wp) {
    if (wp < w) { woff0 += sC0[wp * 8 + e1]; woff1 += sC1[wp * 8 + e2]; }
  }
  int b = blockIdx.x;
  int pos0 = off[b * 8 + e1] + woff0 + wr0;
  int pos1 = off[(256 + b) * 8 + e2] + woff1 + wr1;
  float4 v = wd[t];
  float sv = 0.f;
  if (pos0 < CAP) sv += v.x * v.z;
  if (pos1 < CAP) sv += v.y * v.w;
  s[t] = sv;
}

// --- K3: per-row (B=8 rows of N=8192) log_softmax ---
__global__ __launch_bounds__(1024) void k_lsm(const float* __restrict__ s,
                                              float* __restrict__ out) {
  __shared__ float sRa[16], sRb[16];
  int tid = threadIdx.x, lane = tid & 63, w = tid >> 6;
  size_t base = (size_t)blockIdx.x * 8192;
  float v[8];
#pragma unroll
  for (int j = 0; j < 8; ++j) v[j] = s[base + tid + j * 1024];
  float mx = v[0];
#pragma unroll
  for (int j = 1; j < 8; ++j) mx = fmaxf(mx, v[j]);
#pragma unroll
  for (int m = 1; m < 64; m <<= 1) mx = fmaxf(mx, __shfl_xor(mx, m, 64));
  if (lane == 0) sRa[w] = mx;
  __syncthreads();
#pragma unroll
  for (int i = 0; i < 16; ++i) mx = fmaxf(mx, sRa[i]);
  float sum = 0.f;
#pragma unroll
  for (int j = 0; j < 8; ++j) sum += expf(v[j] - mx);
#pragma unroll
  for (int m = 1; m < 64; m <<= 1) sum += __shfl_xor(sum, m, 64);
  if (lane == 0) sRb[w] = sum;
  __syncthreads();
  float tot = 0.f;
#pragma unroll
  for (int i = 0; i < 16; ++i) tot += sRb[i];
  float lse = logf(tot);
#pragma unroll
  for (int j = 0; j < 8; ++j) out[base + tid + j * 1024] = v[j] - mx - lse;
}

extern "C" void kernel_launch(void* const* d_in, const int* in_sizes, int n_in,
                              void* d_out, int out_size, void* d_ws, size_t ws_size,
                              hipStream_t stream) {
  const float* x  = (const float*)d_in[0];
  const float* Wg = (const float*)d_in[1];
  const float* W1 = (const float*)d_in[2];
  const float* b1 = (const float*)d_in[3];
  const float* W2 = (const float*)d_in[4];
  const float* b2 = (const float*)d_in[5];
  float* out = (float*)d_out;
  char* ws = (char*)d_ws;

  float*  w2s  = (float*)(ws);                          // 16 KB
  float*  wT   = (float*)(ws + (16u << 10));            // 32 KB: [16][512]
  float*  beta = (float*)(ws + (48u << 10));            // 32 B
  float*  dots = (float*)(ws + (64u << 10));            // 4 MB
  char*   p1   = ws + (64u << 10) + (4u << 20);
  float4* wd   = (float4*)(p1);                         // 1 MB
  int*    epk  = (int*)(p1 + (1u << 20));               // 256 KB
  int*    hist = (int*)(p1 + (1u << 20) + (256u << 10));// 16 KB
  int*    offa = (int*)(p1 + (1u << 20) + (272u << 10));// 16 KB
  float*  s    = (float*)(p1 + (1u << 20) + (288u << 10)); // 256 KB

  hipLaunchKernelGGL(k_wgT,    dim3(16),   dim3(256),  0, stream, Wg, wT);
  hipLaunchKernelGGL(k_w2s,    dim3(1024), dim3(256),  0, stream, W2, w2s);
  hipLaunchKernelGGL(k_v_beta, dim3(1025), dim3(256),  0, stream, W1, b1, b2, w2s, wT, beta);
  hipLaunchKernelGGL(k_dots,   dim3(512),  dim3(256),  0, stream, x, wT, dots);
  hipLaunchKernelGGL(k_top2,   dim3(256),  dim3(256),  0, stream, dots, beta, wd, epk, hist);
  hipLaunchKernelGGL(k_scan,   dim3(1),    dim3(256),  0, stream, hist, offa);
  hipLaunchKernelGGL(k_keep,   dim3(256),  dim3(256),  0, stream, epk, wd, offa, s);
  hipLaunchKernelGGL(k_lsm,    dim3(8),    dim3(1024), 0, stream, s, out);
}

// Round 7
// 51.515 us; speedup vs baseline: 2.0628x; 1.1676x over previous
//
#include <hip/hip_runtime.h>

#define T_TOK 65536
#define DDIM 512
#define NEXP 8
#define CAP 16384

__device__ inline float wave_sum(float v) {
#pragma unroll
  for (int m = 1; m < 64; m <<= 1) v += __shfl_xor(v, m, 64);
  return v;
}

template <int CTRL>
__device__ __forceinline__ float dppf(float v) {
  return __int_as_float(
      __builtin_amdgcn_mov_dpp(__float_as_int(v), CTRL, 0xf, 0xf, true));
}
__device__ __forceinline__ void pl32swap(float& a, float& b) {
  asm("v_permlane32_swap_b32 %0, %1" : "+v"(a), "+v"(b));
}
__device__ __forceinline__ void pl16swap(float& a, float& b) {
  asm("v_permlane16_swap_b32 %0, %1" : "+v"(a), "+v"(b));
}

// --- K0a: blocks<1024: w2s[e*H+h]=sum_d W2[e,h,d]; blocks>=1024: wT rows 0..7
// (transposed gate weights wT[e*512+d] = Wg[d*8+e]) ---
__global__ void k_w2s(const float* __restrict__ W2, const float* __restrict__ Wg,
                      float* __restrict__ w2s, float* __restrict__ wT) {
  if (blockIdx.x < 1024) {
    int w = threadIdx.x >> 6, lane = threadIdx.x & 63;
    int row = blockIdx.x * 4 + w;  // < 4096
    const float* p = W2 + (size_t)row * 512;
    float sum = 0.f;
#pragma unroll
    for (int j = 0; j < 8; ++j) sum += p[lane + j * 64];
    sum = wave_sum(sum);
    if (lane == 0) w2s[row] = sum;
  } else {
    int i = (blockIdx.x - 1024) * 256 + threadIdx.x;  // < 4096
    int e = i >> 9, d = i & 511;
    wT[i] = Wg[d * 8 + e];
  }
}

// --- K0b: wT[(8+e)*512+d] = sum_h W1[e,d,h]*w2s[e,h]; last block: beta[e] ---
__global__ void k_v_beta(const float* __restrict__ W1, const float* __restrict__ b1,
                         const float* __restrict__ b2, const float* __restrict__ w2s,
                         float* __restrict__ wT, float* __restrict__ beta) {
  int w = threadIdx.x >> 6, lane = threadIdx.x & 63;
  if (blockIdx.x < 1024) {
    int rid = blockIdx.x * 4 + w;  // rid = e*512 + d
    int e = rid >> 9, d = rid & 511;
    const float* p = W1 + (size_t)rid * 512;
    const float* q = w2s + e * 512;
    float sum = 0.f;
#pragma unroll
    for (int j = 0; j < 8; ++j) { int h = lane + j * 64; sum += p[h] * q[h]; }
    sum = wave_sum(sum);
    if (lane == 0) wT[(size_t)(8 + e) * 512 + d] = sum;
  } else {
#pragma unroll
    for (int r = 0; r < 2; ++r) {
      int e = w + r * 4;
      float sum = 0.f;
#pragma unroll
      for (int j = 0; j < 8; ++j) {
        int i = lane + j * 64;
        sum += b1[e * 512 + i] * w2s[e * 512 + i] + b2[e * 512 + i];
      }
      sum = wave_sum(sum);
      if (lane == 0) beta[e] = sum;
    }
  }
}

// --- K1: per token 16 dots ([0..7]=logits, [8..15]=x·v).
// Wave-pair split: wave parity wo owns 8 outputs (64 weight VGPRs -> fits
// 4 waves/SIMD); waves wo=0/1 stream the SAME 32 tokens (2nd read hits L1/L2).
// 4-slot rotating register prefetch (3 tokens in flight), no LDS, no barriers.
// Per-token 8 dot sums via pure-VALU butterfly: permlane32/16_swap + DPP.
__global__ __launch_bounds__(256, 4) void k_dots(const float* __restrict__ x,
                                                 const float* __restrict__ wT,
                                                 float* __restrict__ dots) {
  const int lane = threadIdx.x & 63;
  const int wave = threadIdx.x >> 6;
  const int wo = wave & 1;          // output group (0: logits, 1: x·v)
  const int tset = wave >> 1;       // token half within block
  const int tbase = blockIdx.x * 64 + tset * 32;

  float w[8][8];
#pragma unroll
  for (int o = 0; o < 8; ++o) {
    const float* wp = wT + (size_t)(wo * 8 + o) * 512 + 8 * lane;
    float4 wa = *reinterpret_cast<const float4*>(wp);
    float4 wb = *reinterpret_cast<const float4*>(wp + 4);
    w[o][0] = wa.x; w[o][1] = wa.y; w[o][2] = wa.z; w[o][3] = wa.w;
    w[o][4] = wb.x; w[o][5] = wb.y; w[o][6] = wb.z; w[o][7] = wb.w;
  }

  const bool kb3 = (lane & 8) != 0;
  const float* xb = x + (size_t)tbase * 512 + 8 * lane;

  auto proc = [&](int tok, float4 x0, float4 x1) {
    float p[8];
#pragma unroll
    for (int o = 0; o < 8; ++o)
      p[o] = x0.x * w[o][0] + x0.y * w[o][1] + x0.z * w[o][2] + x0.w * w[o][3] +
             x1.x * w[o][4] + x1.y * w[o][5] + x1.z * w[o][6] + x1.w * w[o][7];
    // mask32: o bit2 <- lane bit5
    float a[4];
#pragma unroll
    for (int j = 0; j < 4; ++j) {
      float u = p[j], v = p[j + 4];
      pl32swap(u, v);
      a[j] = u + v;
    }
    // mask16: o bit1 <- lane bit4
    float b[2];
#pragma unroll
    for (int j = 0; j < 2; ++j) {
      float u = a[j], v = a[j + 2];
      pl16swap(u, v);
      b[j] = u + v;
    }
    // mask8 via row_ror:8: o bit0 <- lane bit3
    float snd = kb3 ? b[0] : b[1];
    float kp  = kb3 ? b[1] : b[0];
    float c = kp + dppf<0x128>(snd);
    // fold lane bits 2,1,0
    c += dppf<0x141>(c);  // row_half_mirror: l^7
    c += dppf<0x4E>(c);   // quad_perm [2,3,0,1]: l^2
    c += dppf<0xB1>(c);   // quad_perm [1,0,3,2]: l^1
    if ((lane & 7) == 0)
      dots[(size_t)tok * 16 + wo * 8 + (lane >> 3)] = c;
  };

  float4 s00, s01, s10, s11, s20, s21, s30, s31;
  const float* q;
  q = xb;              s00 = *reinterpret_cast<const float4*>(q); s01 = *reinterpret_cast<const float4*>(q + 4);
  q = xb + 512;        s10 = *reinterpret_cast<const float4*>(q); s11 = *reinterpret_cast<const float4*>(q + 4);
  q = xb + 1024;       s20 = *reinterpret_cast<const float4*>(q); s21 = *reinterpret_cast<const float4*>(q + 4);

#pragma unroll
  for (int r = 0; r < 32; r += 4) {
    q = xb + (size_t)(r + 3) * 512;
    s30 = *reinterpret_cast<const float4*>(q); s31 = *reinterpret_cast<const float4*>(q + 4);
    proc(tbase + r, s00, s01);
    if (r + 4 < 32) {
      q = xb + (size_t)(r + 4) * 512;
      s00 = *reinterpret_cast<const float4*>(q); s01 = *reinterpret_cast<const float4*>(q + 4);
    }
    proc(tbase + r + 1, s10, s11);
    if (r + 5 < 32) {
      q = xb + (size_t)(r + 5) * 512;
      s10 = *reinterpret_cast<const float4*>(q); s11 = *reinterpret_cast<const float4*>(q + 4);
    }
    proc(tbase + r + 2, s20, s21);
    if (r + 6 < 32) {
      q = xb + (size_t)(r + 6) * 512;
      s20 = *reinterpret_cast<const float4*>(q); s21 = *reinterpret_cast<const float4*>(q + 4);
    }
    proc(tbase + r + 3, s30, s31);
  }
}

// --- K2a: top-2 select + renorm weights + per-block expert histograms ---
__global__ void k_top2(const float* __restrict__ dots, const float* __restrict__ beta,
                       float4* __restrict__ wd, int* __restrict__ epk,
                       int* __restrict__ hist) {
  __shared__ int c0[8], c1[8];
  int tid = threadIdx.x;
  if (tid < 8) { c0[tid] = 0; c1[tid] = 0; }
  __syncthreads();
  int t = blockIdx.x * 256 + tid;
  const float* p = dots + (size_t)t * 16;
  float l[8], dv[8];
#pragma unroll
  for (int e = 0; e < 8; ++e) { l[e] = p[e]; dv[e] = p[8 + e]; }
  int e1 = 0; float v1 = l[0];
#pragma unroll
  for (int e = 1; e < 8; ++e) if (l[e] > v1) { v1 = l[e]; e1 = e; }  // ties -> low idx
  int e2 = 0; float v2 = -3.4e38f;
#pragma unroll
  for (int e = 0; e < 8; ++e) if (e != e1 && l[e] > v2) { v2 = l[e]; e2 = e; }
  float wexp = expf(v2 - v1);
  float w1 = 1.f / (1.f + wexp);
  float w2 = wexp * w1;
  float d1 = 0.f, d2 = 0.f;
#pragma unroll
  for (int e = 0; e < 8; ++e) {
    d1 = (e == e1) ? dv[e] : d1;
    d2 = (e == e2) ? dv[e] : d2;
  }
  float4 o; o.x = w1; o.y = w2; o.z = d1 + beta[e1]; o.w = d2 + beta[e2];
  wd[t] = o;
  epk[t] = e1 | (e2 << 8);
  atomicAdd(&c0[e1], 1);
  atomicAdd(&c1[e2], 1);
  __syncthreads();
  if (tid < 8) {
    hist[blockIdx.x * 8 + tid] = c0[tid];
    hist[(256 + blockIdx.x) * 8 + tid] = c1[tid];
  }
}

// --- K2b: exclusive scan of 512 block-histograms (k-major order), per expert.
// 512 threads: (g,e) scans 8 rows; 6-step Hillis-Steele over 64 group totals. ---
__global__ __launch_bounds__(512) void k_scan(const int* __restrict__ hist,
                                              int* __restrict__ off) {
  __shared__ int sH[4096];
  __shared__ int sT[512];
  int tid = threadIdx.x;
#pragma unroll
  for (int i = tid; i < 4096; i += 512) sH[i] = hist[i];
  __syncthreads();
  int e = tid & 7, g = tid >> 3;  // g < 64, each scans 8 rows
  int run = 0;
#pragma unroll
  for (int i = g * 8; i < g * 8 + 8; ++i) {
    int cv = sH[i * 8 + e]; sH[i * 8 + e] = run; run += cv;
  }
  sT[tid] = run;
  __syncthreads();
  int inc = run;
#pragma unroll
  for (int st = 1; st < 64; st <<= 1) {
    int add = (g >= st) ? sT[tid - st * 8] : 0;
    __syncthreads();
    inc += add;
    sT[tid] = inc;
    __syncthreads();
  }
  int exc = inc - run;
#pragma unroll
  for (int i = g * 8; i < g * 8 + 8; ++i) sH[i * 8 + e] += exc;
  __syncthreads();
#pragma unroll
  for (int i = tid; i < 4096; i += 512) off[i] = sH[i];
}

// --- K2c: stable intra-block ranks via ballots -> pos -> keep -> s[t] ---
__global__ void k_keep(const int* __restrict__ epk, const float4* __restrict__ wd,
                       const int* __restrict__ off, float* __restrict__ s) {
  __shared__ int sC0[32], sC1[32];
  int tid = threadIdx.x, lane = tid & 63, w = tid >> 6;
  int t = blockIdx.x * 256 + tid;
  int ep = epk[t]; int e1 = ep & 255, e2 = ep >> 8;
  unsigned long long lt = (1ull << lane) - 1ull;
  int wr0 = 0, wr1 = 0;
#pragma unroll
  for (int e = 0; e < 8; ++e) {
    unsigned long long m0 = __ballot(e1 == e);
    unsigned long long m1 = __ballot(e2 == e);
    if (e == e1) wr0 = __popcll(m0 & lt);
    if (e == e2) wr1 = __popcll(m1 & lt);
    if (lane == 0) { sC0[w * 8 + e] = __popcll(m0); sC1[w * 8 + e] = __popcll(m1); }
  }
  __syncthreads();
  int woff0 = 0, woff1 = 0;
  for (int wp = 0; wp < 4; ++wp) {
    if (wp < w) { woff0 += sC0[wp * 8 + e1]; woff1 += sC1[wp * 8 + e2]; }
  }
  int b = blockIdx.x;
  int pos0 = off[b * 8 + e1] + woff0 + wr0;
  int pos1 = off[(256 + b) * 8 + e2] + woff1 + wr1;
  float4 v = wd[t];
  float sv = 0.f;
  if (pos0 < CAP) sv += v.x * v.z;
  if (pos1 < CAP) sv += v.y * v.w;
  s[t] = sv;
}

// --- K3: per-row (B=8 rows of N=8192) log_softmax ---
__global__ __launch_bounds__(1024) void k_lsm(const float* __restrict__ s,
                                              float* __restrict__ out) {
  __shared__ float sRa[16], sRb[16];
  int tid = threadIdx.x, lane = tid & 63, w = tid >> 6;
  size_t base = (size_t)blockIdx.x * 8192;
  float v[8];
#pragma unroll
  for (int j = 0; j < 8; ++j) v[j] = s[base + tid + j * 1024];
  float mx = v[0];
#pragma unroll
  for (int j = 1; j < 8; ++j) mx = fmaxf(mx, v[j]);
#pragma unroll
  for (int m = 1; m < 64; m <<= 1) mx = fmaxf(mx, __shfl_xor(mx, m, 64));
  if (lane == 0) sRa[w] = mx;
  __syncthreads();
#pragma unroll
  for (int i = 0; i < 16; ++i) mx = fmaxf(mx, sRa[i]);
  float sum = 0.f;
#pragma unroll
  for (int j = 0; j < 8; ++j) sum += expf(v[j] - mx);
#pragma unroll
  for (int m = 1; m < 64; m <<= 1) sum += __shfl_xor(sum, m, 64);
  if (lane == 0) sRb[w] = sum;
  __syncthreads();
  float tot = 0.f;
#pragma unroll
  for (int i = 0; i < 16; ++i) tot += sRb[i];
  float lse = logf(tot);
#pragma unroll
  for (int j = 0; j < 8; ++j) out[base + tid + j * 1024] = v[j] - mx - lse;
}

extern "C" void kernel_launch(void* const* d_in, const int* in_sizes, int n_in,
                              void* d_out, int out_size, void* d_ws, size_t ws_size,
                              hipStream_t stream) {
  const float* x  = (const float*)d_in[0];
  const float* Wg = (const float*)d_in[1];
  const float* W1 = (const float*)d_in[2];
  const float* b1 = (const float*)d_in[3];
  const float* W2 = (const float*)d_in[4];
  const float* b2 = (const float*)d_in[5];
  float* out = (float*)d_out;
  char* ws = (char*)d_ws;

  float*  w2s  = (float*)(ws);                          // 16 KB
  float*  wT   = (float*)(ws + (16u << 10));            // 32 KB: [16][512]
  float*  beta = (float*)(ws + (48u << 10));            // 32 B
  float*  dots = (float*)(ws + (64u << 10));            // 4 MB
  char*   p1   = ws + (64u << 10) + (4u << 20);
  float4* wd   = (float4*)(p1);                         // 1 MB
  int*    epk  = (int*)(p1 + (1u << 20));               // 256 KB
  int*    hist = (int*)(p1 + (1u << 20) + (256u << 10));// 16 KB
  int*    offa = (int*)(p1 + (1u << 20) + (272u << 10));// 16 KB
  float*  s    = (float*)(p1 + (1u << 20) + (288u << 10)); // 256 KB

  hipLaunchKernelGGL(k_w2s,    dim3(1040), dim3(256),  0, stream, W2, Wg, w2s, wT);
  hipLaunchKernelGGL(k_v_beta, dim3(1025), dim3(256),  0, stream, W1, b1, b2, w2s, wT, beta);
  hipLaunchKernelGGL(k_dots,   dim3(1024), dim3(256),  0, stream, x, wT, dots);
  hipLaunchKernelGGL(k_top2,   dim3(256),  dim3(256),  0, stream, dots, beta, wd, epk, hist);
  hipLaunchKernelGGL(k_scan,   dim3(1),    dim3(512),  0, stream, hist, offa);
  hipLaunchKernelGGL(k_keep,   dim3(256),  dim3(256),  0, stream, epk, wd, offa, s);
  hipLaunchKernelGGL(k_lsm,    dim3(8),    dim3(1024), 0, stream, s, out);
}

// Round 10
// 48.691 us; speedup vs baseline: 2.1825x; 1.0580x over previous
//
#include <hip/hip_runtime.h>

#define T_TOK 65536
#define DDIM 512
#define NEXP 8
#define CAP 16384

__device__ inline float wave_sum(float v) {
#pragma unroll
  for (int m = 1; m < 64; m <<= 1) v += __shfl_xor(v, m, 64);
  return v;
}

template <int CTRL>
__device__ __forceinline__ float dppf(float v) {
  return __int_as_float(
      __builtin_amdgcn_mov_dpp(__float_as_int(v), CTRL, 0xf, 0xf, true));
}
__device__ __forceinline__ void pl32swap(float& a, float& b) {
  asm("v_permlane32_swap_b32 %0, %1" : "+v"(a), "+v"(b));
}
__device__ __forceinline__ void pl16swap(float& a, float& b) {
  asm("v_permlane16_swap_b32 %0, %1" : "+v"(a), "+v"(b));
}

// --- K0a: blocks<1024: w2s[e*H+h]=sum_d W2[e,h,d]; blocks>=1024: wT rows 0..7
// (transposed gate weights wT[e*512+d] = Wg[d*8+e]) ---
__global__ void k_w2s(const float* __restrict__ W2, const float* __restrict__ Wg,
                      float* __restrict__ w2s, float* __restrict__ wT) {
  if (blockIdx.x < 1024) {
    int w = threadIdx.x >> 6, lane = threadIdx.x & 63;
    int row = blockIdx.x * 4 + w;  // < 4096
    const float* p = W2 + (size_t)row * 512;
    float sum = 0.f;
#pragma unroll
    for (int j = 0; j < 8; ++j) sum += p[lane + j * 64];
    sum = wave_sum(sum);
    if (lane == 0) w2s[row] = sum;
  } else {
    int i = (blockIdx.x - 1024) * 256 + threadIdx.x;  // < 4096
    int e = i >> 9, d = i & 511;
    wT[i] = Wg[d * 8 + e];
  }
}

// --- K0b: wT[(8+e)*512+d] = sum_h W1[e,d,h]*w2s[e,h]; last block: beta[e] ---
__global__ void k_v_beta(const float* __restrict__ W1, const float* __restrict__ b1,
                         const float* __restrict__ b2, const float* __restrict__ w2s,
                         float* __restrict__ wT, float* __restrict__ beta) {
  int w = threadIdx.x >> 6, lane = threadIdx.x & 63;
  if (blockIdx.x < 1024) {
    int rid = blockIdx.x * 4 + w;  // rid = e*512 + d
    int e = rid >> 9, d = rid & 511;
    const float* p = W1 + (size_t)rid * 512;
    const float* q = w2s + e * 512;
    float sum = 0.f;
#pragma unroll
    for (int j = 0; j < 8; ++j) { int h = lane + j * 64; sum += p[h] * q[h]; }
    sum = wave_sum(sum);
    if (lane == 0) wT[(size_t)(8 + e) * 512 + d] = sum;
  } else {
#pragma unroll
    for (int r = 0; r < 2; ++r) {
      int e = w + r * 4;
      float sum = 0.f;
#pragma unroll
      for (int j = 0; j < 8; ++j) {
        int i = lane + j * 64;
        sum += b1[e * 512 + i] * w2s[e * 512 + i] + b2[e * 512 + i];
      }
      sum = wave_sum(sum);
      if (lane == 0) beta[e] = sum;
    }
  }
}

// --- K1: 256 tokens/block, 1024 threads (16 waves). GEMV exactly as R7:
// wave parity wo owns 8 outputs in VGPRs; wave pair streams 32 tokens.
// Dots land in LDS sD[256][17]. Tail = R7's k_top2 body VERBATIM (tid<256),
// with block-level barriers; writes wd, epk, per-block c0/c1 histograms. ---
__global__ __launch_bounds__(1024, 4) void k_dots(const float* __restrict__ x,
                                                  const float* __restrict__ wT,
                                                  const float* __restrict__ beta,
                                                  float4* __restrict__ wd,
                                                  int* __restrict__ epk,
                                                  int* __restrict__ hist) {
  __shared__ float sD[256 * 17];  // 17 coprime 32 -> benign padding
  __shared__ int c0[8], c1[8];
  const int tid = threadIdx.x;
  const int lane = tid & 63;
  const int wave = tid >> 6;        // 0..15
  const int wo = wave & 1;          // output group (0: logits, 1: x·v)
  const int tset = wave >> 1;       // 0..7: 32-token slice within block
  const int tbase = blockIdx.x * 256 + tset * 32;

  float w[8][8];
#pragma unroll
  for (int o = 0; o < 8; ++o) {
    const float* wp = wT + (size_t)(wo * 8 + o) * 512 + 8 * lane;
    float4 wa = *reinterpret_cast<const float4*>(wp);
    float4 wb = *reinterpret_cast<const float4*>(wp + 4);
    w[o][0] = wa.x; w[o][1] = wa.y; w[o][2] = wa.z; w[o][3] = wa.w;
    w[o][4] = wb.x; w[o][5] = wb.y; w[o][6] = wb.z; w[o][7] = wb.w;
  }

  const bool kb3 = (lane & 8) != 0;
  const float* xb = x + (size_t)tbase * 512 + 8 * lane;

  auto proc = [&](int r, float4 x0, float4 x1) {
    float p[8];
#pragma unroll
    for (int o = 0; o < 8; ++o)
      p[o] = x0.x * w[o][0] + x0.y * w[o][1] + x0.z * w[o][2] + x0.w * w[o][3] +
             x1.x * w[o][4] + x1.y * w[o][5] + x1.z * w[o][6] + x1.w * w[o][7];
    float a[4];
#pragma unroll
    for (int j = 0; j < 4; ++j) {
      float u = p[j], v = p[j + 4];
      pl32swap(u, v);
      a[j] = u + v;
    }
    float b[2];
#pragma unroll
    for (int j = 0; j < 2; ++j) {
      float u = a[j], v = a[j + 2];
      pl16swap(u, v);
      b[j] = u + v;
    }
    float snd = kb3 ? b[0] : b[1];
    float kp  = kb3 ? b[1] : b[0];
    float c = kp + dppf<0x128>(snd);
    c += dppf<0x141>(c);  // row_half_mirror: l^7
    c += dppf<0x4E>(c);   // quad_perm [2,3,0,1]: l^2
    c += dppf<0xB1>(c);   // quad_perm [1,0,3,2]: l^1
    if ((lane & 7) == 0)
      sD[(tset * 32 + r) * 17 + wo * 8 + (lane >> 3)] = c;
  };

  float4 s00, s01, s10, s11, s20, s21, s30, s31;
  const float* q;
  q = xb;        s00 = *reinterpret_cast<const float4*>(q); s01 = *reinterpret_cast<const float4*>(q + 4);
  q = xb + 512;  s10 = *reinterpret_cast<const float4*>(q); s11 = *reinterpret_cast<const float4*>(q + 4);
  q = xb + 1024; s20 = *reinterpret_cast<const float4*>(q); s21 = *reinterpret_cast<const float4*>(q + 4);

#pragma unroll
  for (int r = 0; r < 32; r += 4) {
    q = xb + (size_t)(r + 3) * 512;
    s30 = *reinterpret_cast<const float4*>(q); s31 = *reinterpret_cast<const float4*>(q + 4);
    proc(r, s00, s01);
    if (r + 4 < 32) {
      q = xb + (size_t)(r + 4) * 512;
      s00 = *reinterpret_cast<const float4*>(q); s01 = *reinterpret_cast<const float4*>(q + 4);
    }
    proc(r + 1, s10, s11);
    if (r + 5 < 32) {
      q = xb + (size_t)(r + 5) * 512;
      s10 = *reinterpret_cast<const float4*>(q); s11 = *reinterpret_cast<const float4*>(q + 4);
    }
    proc(r + 2, s20, s21);
    if (r + 6 < 32) {
      q = xb + (size_t)(r + 6) * 512;
      s20 = *reinterpret_cast<const float4*>(q); s21 = *reinterpret_cast<const float4*>(q + 4);
    }
    proc(r + 3, s30, s31);
  }

  __syncthreads();  // sD complete
  if (tid < 8) { c0[tid] = 0; c1[tid] = 0; }
  __syncthreads();  // zeros visible
  if (tid < 256) {  // === R7 k_top2 body, dots[] -> sD ===
    const int t = blockIdx.x * 256 + tid;
    float l[8], dv[8];
#pragma unroll
    for (int e = 0; e < 8; ++e) { l[e] = sD[tid * 17 + e]; dv[e] = sD[tid * 17 + 8 + e]; }
    int e1 = 0; float v1 = l[0];
#pragma unroll
    for (int e = 1; e < 8; ++e) if (l[e] > v1) { v1 = l[e]; e1 = e; }  // ties -> low idx
    int e2 = 0; float v2 = -3.4e38f;
#pragma unroll
    for (int e = 0; e < 8; ++e) if (e != e1 && l[e] > v2) { v2 = l[e]; e2 = e; }
    float wexp = expf(v2 - v1);  // renormalized top-2 softmax
    float w1 = 1.f / (1.f + wexp);
    float w2 = wexp * w1;
    float d1 = 0.f, d2 = 0.f;
#pragma unroll
    for (int e = 0; e < 8; ++e) {
      d1 = (e == e1) ? dv[e] : d1;
      d2 = (e == e2) ? dv[e] : d2;
    }
    float4 o; o.x = w1; o.y = w2; o.z = d1 + beta[e1]; o.w = d2 + beta[e2];
    wd[t] = o;
    epk[t] = e1 | (e2 << 8);
    atomicAdd(&c0[e1], 1);
    atomicAdd(&c1[e2], 1);
  }
  __syncthreads();  // counts final
  if (tid < 8) {
    hist[blockIdx.x * 8 + tid] = c0[tid];
    hist[(256 + blockIdx.x) * 8 + tid] = c1[tid];
  }
}

// --- K2: exclusive scan of 512 block-histograms (k-major order), per expert.
// (R7 version, verbatim) ---
__global__ __launch_bounds__(512) void k_scan(const int* __restrict__ hist,
                                              int* __restrict__ off) {
  __shared__ int sH[4096];
  __shared__ int sT[512];
  int tid = threadIdx.x;
#pragma unroll
  for (int i = tid; i < 4096; i += 512) sH[i] = hist[i];
  __syncthreads();
  int e = tid & 7, g = tid >> 3;  // g < 64, each scans 8 rows
  int run = 0;
#pragma unroll
  for (int i = g * 8; i < g * 8 + 8; ++i) {
    int cv = sH[i * 8 + e]; sH[i * 8 + e] = run; run += cv;
  }
  sT[tid] = run;
  __syncthreads();
  int inc = run;
#pragma unroll
  for (int st = 1; st < 64; st <<= 1) {
    int add = (g >= st) ? sT[tid - st * 8] : 0;
    __syncthreads();
    inc += add;
    sT[tid] = inc;
    __syncthreads();
  }
  int exc = inc - run;
#pragma unroll
  for (int i = g * 8; i < g * 8 + 8; ++i) sH[i * 8 + e] += exc;
  __syncthreads();
#pragma unroll
  for (int i = tid; i < 4096; i += 512) off[i] = sH[i];
}

// --- K3: stable intra-block ranks via ballots -> pos -> keep -> s[t]
// (R7 version, verbatim) ---
__global__ void k_keep(const int* __restrict__ epk, const float4* __restrict__ wd,
                       const int* __restrict__ off, float* __restrict__ s) {
  __shared__ int sC0[32], sC1[32];
  int tid = threadIdx.x, lane = tid & 63, w = tid >> 6;
  int t = blockIdx.x * 256 + tid;
  int ep = epk[t]; int e1 = ep & 255, e2 = ep >> 8;
  unsigned long long lt = (1ull << lane) - 1ull;
  int wr0 = 0, wr1 = 0;
#pragma unroll
  for (int e = 0; e < 8; ++e) {
    unsigned long long m0 = __ballot(e1 == e);
    unsigned long long m1 = __ballot(e2 == e);
    if (e == e1) wr0 = __popcll(m0 & lt);
    if (e == e2) wr1 = __popcll(m1 & lt);
    if (lane == 0) { sC0[w * 8 + e] = __popcll(m0); sC1[w * 8 + e] = __popcll(m1); }
  }
  __syncthreads();
  int woff0 = 0, woff1 = 0;
  for (int wp = 0; wp < 4; ++wp) {
    if (wp < w) { woff0 += sC0[wp * 8 + e1]; woff1 += sC1[wp * 8 + e2]; }
  }
  int b = blockIdx.x;
  int pos0 = off[b * 8 + e1] + woff0 + wr0;
  int pos1 = off[(256 + b) * 8 + e2] + woff1 + wr1;
  float4 v = wd[t];
  float sv = 0.f;
  if (pos0 < CAP) sv += v.x * v.z;
  if (pos1 < CAP) sv += v.y * v.w;
  s[t] = sv;
}

// --- K4: per-row (B=8 rows of N=8192) log_softmax (R7 version, verbatim) ---
__global__ __launch_bounds__(1024) void k_lsm(const float* __restrict__ s,
                                              float* __restrict__ out) {
  __shared__ float sRa[16], sRb[16];
  int tid = threadIdx.x, lane = tid & 63, w = tid >> 6;
  size_t base = (size_t)blockIdx.x * 8192;
  float v[8];
#pragma unroll
  for (int j = 0; j < 8; ++j) v[j] = s[base + tid + j * 1024];
  float mx = v[0];
#pragma unroll
  for (int j = 1; j < 8; ++j) mx = fmaxf(mx, v[j]);
#pragma unroll
  for (int m = 1; m < 64; m <<= 1) mx = fmaxf(mx, __shfl_xor(mx, m, 64));
  if (lane == 0) sRa[w] = mx;
  __syncthreads();
#pragma unroll
  for (int i = 0; i < 16; ++i) mx = fmaxf(mx, sRa[i]);
  float sum = 0.f;
#pragma unroll
  for (int j = 0; j < 8; ++j) sum += expf(v[j] - mx);
#pragma unroll
  for (int m = 1; m < 64; m <<= 1) sum += __shfl_xor(sum, m, 64);
  if (lane == 0) sRb[w] = sum;
  __syncthreads();
  float tot = 0.f;
#pragma unroll
  for (int i = 0; i < 16; ++i) tot += sRb[i];
  float lse = logf(tot);
#pragma unroll
  for (int j = 0; j < 8; ++j) out[base + tid + j * 1024] = v[j] - mx - lse;
}

extern "C" void kernel_launch(void* const* d_in, const int* in_sizes, int n_in,
                              void* d_out, int out_size, void* d_ws, size_t ws_size,
                              hipStream_t stream) {
  const float* x  = (const float*)d_in[0];
  const float* Wg = (const float*)d_in[1];
  const float* W1 = (const float*)d_in[2];
  const float* b1 = (const float*)d_in[3];
  const float* W2 = (const float*)d_in[4];
  const float* b2 = (const float*)d_in[5];
  float* out = (float*)d_out;
  char* ws = (char*)d_ws;

  float*  w2s  = (float*)(ws);                          // 16 KB
  float*  wT   = (float*)(ws + (16u << 10));            // 32 KB: [16][512]
  float*  beta = (float*)(ws + (48u << 10));            // 32 B
  float4* wd   = (float4*)(ws + (64u << 10));           // 1 MB
  int*    epk  = (int*)(ws + (64u << 10) + (1u << 20)); // 256 KB
  int*    hist = (int*)(ws + (64u << 10) + (1u << 20) + (256u << 10)); // 16 KB
  int*    offa = (int*)(ws + (64u << 10) + (1u << 20) + (272u << 10)); // 16 KB
  float*  s    = (float*)(ws + (64u << 10) + (1u << 20) + (288u << 10)); // 256 KB

  hipLaunchKernelGGL(k_w2s,    dim3(1040), dim3(256),  0, stream, W2, Wg, w2s, wT);
  hipLaunchKernelGGL(k_v_beta, dim3(1025), dim3(256),  0, stream, W1, b1, b2, w2s, wT, beta);
  hipLaunchKernelGGL(k_dots,   dim3(256),  dim3(1024), 0, stream, x, wT, beta, wd, epk, hist);
  hipLaunchKernelGGL(k_scan,   dim3(1),    dim3(512),  0, stream, hist, offa);
  hipLaunchKernelGGL(k_keep,   dim3(256),  dim3(256),  0, stream, epk, wd, offa, s);
  hipLaunchKernelGGL(k_lsm,    dim3(8),    dim3(1024), 0, stream, s, out);
}